// Round 8
// baseline (148.116 us; speedup 1.0000x reference)
//
#include <hip/hip_runtime.h>
#include <math.h>

#define Bn 32
#define Cn 512
#define Hn 56
#define Wn 56
#define HW (Hn*Wn)           // 3136
#define NPLANE (Bn*Cn)       // 16384
#define F4P (HW/4)           // 784

#define NCHUNK 4             // 8 batches per chunk: 51 MB x-chunk, L3-safe
#define BPC (Bn/NCHUNK)      // batches per chunk = 8
#define PPC (BPC*Cn)         // planes per chunk = 4096

typedef float f4 __attribute__((ext_vector_type(4)));

// ---------------------------------------------------------------------------
// Pool kernel (chunked): one block per plane, planes [off, off+PPC).
// Identical math to the R4 known-good version.
// ---------------------------------------------------------------------------
__global__ __launch_bounds__(256) void pool_conv_kernel(
    const float* __restrict__ x,
    const float* __restrict__ w1,   // [3][3][3] (ic,ky,kx)
    const float* __restrict__ w2,   // [3][3]
    float* __restrict__ s0,         // [NPLANE]
    int off)                        // plane offset of this chunk
{
    __shared__ float plane[HW];     // 12544 B
    __shared__ float rs[Hn * 4];
    __shared__ float y4[16];

    const int bc = off + blockIdx.x;
    const int t  = threadIdx.x;
    const float* src = x + (size_t)bc * HW;

    for (int f = t; f < F4P; f += 256)
        ((f4*)plane)[f] = ((const f4*)src)[f];
    __syncthreads();

    if (t < Hn * 4) {
        const int h = t >> 2, j = t & 3;
        const float* row = plane + h * Wn + j * 14;
        float s = 0.f;
        #pragma unroll
        for (int e = 0; e < 14; ++e) s += row[e];
        rs[h * 4 + j] = s;
    }
    __syncthreads();

    if (t < 16) {
        const int i = t >> 2, j = t & 3;
        float s = 0.f;
        #pragma unroll
        for (int r = 0; r < 14; ++r) s += rs[(i * 14 + r) * 4 + j];
        y4[i * 4 + j] = s * (1.0f / 196.0f);
    }
    __syncthreads();

    if (t == 0) {
        float y2[2][2];
        #pragma unroll
        for (int p = 0; p < 2; ++p)
            #pragma unroll
            for (int q = 0; q < 2; ++q)
                y2[p][q] = 0.25f * (y4[(2*p)*4 + 2*q]   + y4[(2*p)*4 + 2*q+1]
                                  + y4[(2*p+1)*4 + 2*q] + y4[(2*p+1)*4 + 2*q+1]);
        const float y1 = 0.25f * (y2[0][0] + y2[0][1] + y2[1][0] + y2[1][1]);

        float z[2][2];
        #pragma unroll
        for (int oy = 0; oy < 2; ++oy)
            #pragma unroll
            for (int ox = 0; ox < 2; ++ox) {
                float acc = 0.f;
                #pragma unroll
                for (int ky = 0; ky < 3; ++ky)
                    #pragma unroll
                    for (int kx = 0; kx < 3; ++kx) {
                        const int yy = oy + ky, xx = ox + kx;
                        acc += y1                   * w1[0*9 + ky*3 + kx];
                        acc += y2[yy >> 1][xx >> 1] * w1[1*9 + ky*3 + kx];
                        acc += y4[yy*4 + xx]        * w1[2*9 + ky*3 + kx];
                    }
                z[oy][ox] = acc;
            }

        s0[bc] = z[0][0] * w2[1*3+1] + z[0][1] * w2[1*3+2]
               + z[1][0] * w2[2*3+1] + z[1][1] * w2[2*3+2];
    }
}

// ---------------------------------------------------------------------------
// FC + scale kernel (chunked): 64 blocks per batch x BPC batches.
// Block (b_local, kk) recomputes the tiny per-batch FC and rescales its 8
// planes. The x re-read targets the 51 MB chunk that pool just streamed —
// chunk + out-chunk (102 MB) fits in the 256 MB L3, so the re-read hits
// regardless of replacement policy. nt-stores for out kept (harmless).
// ---------------------------------------------------------------------------
__global__ __launch_bounds__(256) void fc_scale_kernel(
    const float* __restrict__ x,
    const float* __restrict__ s0,    // [NPLANE]
    const float* __restrict__ fc1,   // [32][512]
    const float* __restrict__ fc2,   // [512][32]
    float* __restrict__ out,
    int batch_off)                   // first batch of this chunk
{
    __shared__ float sv[Cn];
    __shared__ float hv[32];
    __shared__ float scl[8];

    const int b  = batch_off + (blockIdx.x >> 6);
    const int kk = blockIdx.x & 63;
    const int t  = threadIdx.x;

    for (int c = t; c < Cn; c += 256) sv[c] = s0[b * Cn + c];
    __syncthreads();

    {
        const int r = t >> 3, l8 = t & 7;
        float acc = 0.f;
        for (int c = l8; c < Cn; c += 8) acc += sv[c] * fc1[r * Cn + c];
        acc += __shfl_xor(acc, 1);
        acc += __shfl_xor(acc, 2);
        acc += __shfl_xor(acc, 4);
        if (l8 == 0) hv[r] = fmaxf(acc, 0.f);
    }
    __syncthreads();

    if (t < 8) {
        const int c = kk * 8 + t;
        float acc = 0.f;
        #pragma unroll
        for (int r = 0; r < 32; ++r) acc += hv[r] * fc2[c * 32 + r];
        scl[t] = 1.0f / (1.0f + expf(-acc));
    }
    __syncthreads();

    #pragma unroll
    for (int p = 0; p < 8; ++p) {
        const int plane = b * Cn + kk * 8 + p;
        const float sc = scl[p];
        const f4* px = (const f4*)x   + (size_t)plane * F4P;
        f4*       po = (f4*)out      + (size_t)plane * F4P;
        for (int f = t; f < F4P; f += 256) {
            f4 v = px[f];
            v *= sc;
            __builtin_nontemporal_store(v, po + f);
        }
    }
}

extern "C" void kernel_launch(void* const* d_in, const int* in_sizes, int n_in,
                              void* d_out, int out_size, void* d_ws, size_t ws_size,
                              hipStream_t stream) {
    const float* x   = (const float*)d_in[0];
    const float* w1  = (const float*)d_in[1];
    const float* w2  = (const float*)d_in[2];
    const float* fc1 = (const float*)d_in[3];
    const float* fc2 = (const float*)d_in[4];
    float* out = (float*)d_out;
    float* s0  = (float*)d_ws;          // [NPLANE]

    for (int c = 0; c < NCHUNK; ++c) {
        pool_conv_kernel<<<PPC, 256, 0, stream>>>(x, w1, w2, s0, c * PPC);
        fc_scale_kernel<<<BPC * 64, 256, 0, stream>>>(x, s0, fc1, fc2, out,
                                                      c * BPC);
    }
}

// Round 9
// 117.402 us; speedup vs baseline: 1.2616x; 1.2616x over previous
//
#include <hip/hip_runtime.h>
#include <math.h>

#define Bn 32
#define Cn 512
#define Hn 56
#define Wn 56
#define HW (Hn*Wn)           // 3136
#define NPLANE (Bn*Cn)       // 16384
#define F4P (HW/4)           // 784

typedef float f4 __attribute__((ext_vector_type(4)));

// ---------------------------------------------------------------------------
// Kernel A: per-(b,c) multi-scale pooling + conv chain -> scalar s0[bc]
// One block per plane. Conv tail parallelized over 4 lanes (shuffle combine)
// instead of a ~100-FMA serial t0 chain.
// ---------------------------------------------------------------------------
__global__ __launch_bounds__(256) void pool_conv_kernel(
    const float* __restrict__ x,
    const float* __restrict__ w1,   // [3][3][3] (ic,ky,kx)
    const float* __restrict__ w2,   // [3][3]
    float* __restrict__ s0)         // [NPLANE]
{
    __shared__ float plane[HW];     // 12544 B
    __shared__ float rs[Hn * 4];
    __shared__ float y4[16];

    const int bc = blockIdx.x;
    const int t  = threadIdx.x;
    const float* src = x + (size_t)bc * HW;

    for (int f = t; f < F4P; f += 256)
        ((f4*)plane)[f] = ((const f4*)src)[f];
    __syncthreads();

    if (t < Hn * 4) {
        const int h = t >> 2, j = t & 3;
        const float* row = plane + h * Wn + j * 14;
        float s = 0.f;
        #pragma unroll
        for (int e = 0; e < 14; ++e) s += row[e];
        rs[h * 4 + j] = s;
    }
    __syncthreads();

    if (t < 16) {
        const int i = t >> 2, j = t & 3;
        float s = 0.f;
        #pragma unroll
        for (int r = 0; r < 14; ++r) s += rs[(i * 14 + r) * 4 + j];
        y4[i * 4 + j] = s * (1.0f / 196.0f);
    }
    __syncthreads();

    // 4 lanes: lane (oy,ox) computes z[oy][ox] * its conv2 tap, shuffle-sum.
    // conv2 (pad 1, stride 3, k=3 on 2x2): out = sum z[oy][ox]*w2[1+oy][1+ox]
    if (t < 4) {
        const int oy = t >> 1, ox = t & 1;
        float y2[2][2];
        #pragma unroll
        for (int pp = 0; pp < 2; ++pp)
            #pragma unroll
            for (int q = 0; q < 2; ++q)
                y2[pp][q] = 0.25f * (y4[(2*pp)*4 + 2*q]   + y4[(2*pp)*4 + 2*q+1]
                                   + y4[(2*pp+1)*4 + 2*q] + y4[(2*pp+1)*4 + 2*q+1]);
        const float y1v = 0.25f * (y2[0][0] + y2[0][1] + y2[1][0] + y2[1][1]);

        float acc = 0.f;
        #pragma unroll
        for (int ky = 0; ky < 3; ++ky)
            #pragma unroll
            for (int kx = 0; kx < 3; ++kx) {
                const int yy = oy + ky, xx = ox + kx;
                acc += y1v                  * w1[0*9 + ky*3 + kx];
                acc += y2[yy >> 1][xx >> 1] * w1[1*9 + ky*3 + kx];
                acc += y4[yy*4 + xx]        * w1[2*9 + ky*3 + kx];
            }
        float v = acc * w2[(1 + oy) * 3 + (1 + ox)];
        v += __shfl_xor(v, 1);
        v += __shfl_xor(v, 2);
        if (t == 0) s0[bc] = v;
    }
}

// ---------------------------------------------------------------------------
// Kernel B (fused FC + scale): 2048 blocks; block (b,kk) recomputes the tiny
// per-batch FC (negligible) and rescales its 8 contiguous planes.
// Scale loop: explicit 4-load-per-plane structure, unrolled over 8 planes,
// scales hoisted to registers -> deep ILP, many loads in flight.
// ---------------------------------------------------------------------------
__global__ __launch_bounds__(256) void fc_scale_kernel(
    const float* __restrict__ x,
    const float* __restrict__ s0,    // [NPLANE]
    const float* __restrict__ fc1,   // [32][512]
    const float* __restrict__ fc2,   // [512][32]
    float* __restrict__ out)
{
    __shared__ float sv[Cn];
    __shared__ float hv[32];
    __shared__ float scl[8];

    const int b  = blockIdx.x >> 6;
    const int kk = blockIdx.x & 63;
    const int t  = threadIdx.x;

    for (int c = t; c < Cn; c += 256) sv[c] = s0[b * Cn + c];
    __syncthreads();

    {
        const int r = t >> 3, l8 = t & 7;
        float acc = 0.f;
        for (int c = l8; c < Cn; c += 8) acc += sv[c] * fc1[r * Cn + c];
        acc += __shfl_xor(acc, 1);
        acc += __shfl_xor(acc, 2);
        acc += __shfl_xor(acc, 4);
        if (l8 == 0) hv[r] = fmaxf(acc, 0.f);
    }
    __syncthreads();

    if (t < 8) {
        const int c = kk * 8 + t;
        float acc = 0.f;
        #pragma unroll
        for (int r = 0; r < 32; ++r) acc += hv[r] * fc2[c * 32 + r];
        scl[t] = 1.0f / (1.0f + expf(-acc));
    }
    __syncthreads();

    // hoist scales to registers (static indexing -> stays in VGPRs)
    float scr[8];
    #pragma unroll
    for (int p = 0; p < 8; ++p) scr[p] = scl[p];

    const size_t base = (size_t)(b * Cn + kk * 8) * F4P;
    const f4* px = (const f4*)x + base;
    f4*       po = (f4*)out     + base;

    #pragma unroll
    for (int p = 0; p < 8; ++p) {
        const int o = p * F4P;
        const float sc = scr[p];
        f4 a0 = px[o + t];
        f4 a1 = px[o + t + 256];
        f4 a2 = px[o + t + 512];
        f4 a3;
        if (t < F4P - 768) a3 = px[o + t + 768];   // t < 16
        a0 *= sc; a1 *= sc; a2 *= sc;
        __builtin_nontemporal_store(a0, po + o + t);
        __builtin_nontemporal_store(a1, po + o + t + 256);
        __builtin_nontemporal_store(a2, po + o + t + 512);
        if (t < F4P - 768) {
            a3 *= sc;
            __builtin_nontemporal_store(a3, po + o + t + 768);
        }
    }
}

extern "C" void kernel_launch(void* const* d_in, const int* in_sizes, int n_in,
                              void* d_out, int out_size, void* d_ws, size_t ws_size,
                              hipStream_t stream) {
    const float* x   = (const float*)d_in[0];
    const float* w1  = (const float*)d_in[1];
    const float* w2  = (const float*)d_in[2];
    const float* fc1 = (const float*)d_in[3];
    const float* fc2 = (const float*)d_in[4];
    float* out = (float*)d_out;
    float* s0  = (float*)d_ws;          // [NPLANE]

    pool_conv_kernel<<<NPLANE, 256, 0, stream>>>(x, w1, w2, s0);
    fc_scale_kernel<<<NPLANE / 8, 256, 0, stream>>>(x, s0, fc1, fc2, out);
}